// Round 4
// baseline (314.752 us; speedup 1.0000x reference)
//
#include <hip/hip_runtime.h>

// GraphSAGE 3-layer encoder. R13: fuse gather+linear into k_layer.
// Per block (64 rows): GLL-stage own h rows -> LDS Ah; gather-mean neighbor
// rows (ILP-8) -> LDS Aagg; one barrier; dual GEMM agg@Wl + h@Wr with B
// fragments read directly from L2 (weights 32KB, grid-resident). LDS 32KB ->
// whole 782-block grid co-resident (~4 blocks/CU): gather-phase blocks overlap
// MFMA-phase blocks, AGG HBM round-trip (2x12.8MB/layer) eliminated.
#define N_NODES 50000
#define NP 50048          // padded to 782*64 rows
#define N_EDGES 800000
#define N_GRAPHS 512
#define F 128
#define ELLW 64           // Poisson(16): P(deg>=64) ~ e^-125
#define ZROW N_NODES      // guaranteed all-zero row in X/HA/HB

#define FILL_BLOCKS 3125    // N_EDGES/256, 1 edge/thread
#define CASTX_BLOCKS 3128   // NP*F/8/256
#define CASTW_BLOCKS 48     // 6*16384/8/256

typedef __bf16 bf16x8 __attribute__((ext_vector_type(8)));
typedef float f32x4 __attribute__((ext_vector_type(4)));
typedef float f32x4v __attribute__((ext_vector_type(4)));   // nt-load friendly
typedef unsigned short ushort_t;
typedef unsigned int uint_t;

__device__ inline ushort_t f2bf(float f) {  // RTNE
    uint_t u = __float_as_uint(f);
    u += 0x7FFFu + ((u >> 16) & 1u);
    return (ushort_t)(u >> 16);
}
__device__ inline float bf2f(ushort_t u) {
    return __uint_as_float(((uint_t)u) << 16);
}
__device__ inline uint_t pack2(float a, float b) {
    return (uint_t)f2bf(a) | ((uint_t)f2bf(b) << 16);
}
__device__ inline void addrow(float* a, uint4 v) {
    a[0] += __uint_as_float(v.x << 16); a[1] += __uint_as_float(v.x & 0xFFFF0000u);
    a[2] += __uint_as_float(v.y << 16); a[3] += __uint_as_float(v.y & 0xFFFF0000u);
    a[4] += __uint_as_float(v.z << 16); a[5] += __uint_as_float(v.z & 0xFFFF0000u);
    a[6] += __uint_as_float(v.w << 16); a[7] += __uint_as_float(v.w & 0xFFFF0000u);
}

// ---- merged build: ELL fill (1 edge/thread) + bf16 casts ----
__global__ __launch_bounds__(256) void k_build(
    const float* __restrict__ x,
    const float* __restrict__ w0, const float* __restrict__ w1,
    const float* __restrict__ w2, const float* __restrict__ w3,
    const float* __restrict__ w4, const float* __restrict__ w5,
    const int* __restrict__ src, const int* __restrict__ dst,
    ushort_t* __restrict__ X, ushort_t* __restrict__ WB,
    int* __restrict__ cnt, ushort_t* __restrict__ ell, int cs) {
    int b = blockIdx.x;
    int t = threadIdx.x;
    if (b < FILL_BLOCKS) {
        int e = b * 256 + t;
        int d = dst[e];
        int pos = atomicAdd(&cnt[(size_t)d * cs], 1);
        if (pos < ELLW) ell[((size_t)d << 6) + pos] = (ushort_t)src[e];
    } else if (b < FILL_BLOCKS + CASTX_BLOCKS) {
        int i = ((b - FILL_BLOCKS) * 256 + t) * 8;
        uint4 o = make_uint4(0, 0, 0, 0);
        if (i < N_NODES * F) {  // boundary 8-aligned: no straddle
            f32x4v v0 = __builtin_nontemporal_load((const f32x4v*)&x[i]);
            f32x4v v1 = __builtin_nontemporal_load((const f32x4v*)&x[i + 4]);
            o = make_uint4(pack2(v0.x, v0.y), pack2(v0.z, v0.w),
                           pack2(v1.x, v1.y), pack2(v1.z, v1.w));
        }
        *(uint4*)&X[i] = o;  // pads (>=N_NODES) written as zeros: ZROW source
    } else {
        int idx = (b - FILL_BLOCKS - CASTX_BLOCKS) * 256 + t;  // 8-elem groups
        int m = idx >> 11;
        int o = (idx & 2047) * 8;
        const float* s = w0;
        if (m == 1) s = w1; else if (m == 2) s = w2; else if (m == 3) s = w3;
        else if (m == 4) s = w4; else if (m == 5) s = w5;
        float4 v0 = *(const float4*)&s[o];
        float4 v1 = *(const float4*)&s[o + 4];
        *(uint4*)&WB[m * 16384 + o] =
            make_uint4(pack2(v0.x, v0.y), pack2(v0.z, v0.w),
                       pack2(v1.x, v1.y), pack2(v1.z, v1.w));
    }
}

// ---- fused layer: gather-mean + dual GEMM (agg@Wl + h@Wr) + bias + relu ----
// 782 blocks x 256 thr. LDS: Ah 16KB + Aagg 16KB, [kchunk][row]x16B layout.
__global__ __launch_bounds__(256) void k_layer(const ushort_t* __restrict__ h,
                                               const ushort_t* __restrict__ ell,
                                               const int* __restrict__ cnt,
                                               const ushort_t* __restrict__ Wl,
                                               const ushort_t* __restrict__ Wr,
                                               const float* __restrict__ bias,
                                               ushort_t* __restrict__ out, int cs) {
    __shared__ uint4 AhS[1024];    // 16 KB: h rows, chunk-major [16][64] x16B
    __shared__ uint4 AggS[1024];   // 16 KB: gathered agg rows, same layout
    ushort_t* Ah = (ushort_t*)AhS;
    ushort_t* Agg = (ushort_t*)AggS;

    int t = threadIdx.x;
    int w = t >> 6;
    int lane = t & 63;
    int bm = blockIdx.x * 64;
    int lane16 = t & 15;

    // -- stage own h rows (async GLL, drains at the barrier) --
#pragma unroll
    for (int p = 0; p < 4; p++) {
        int chunkA = p * 4 + w;
        const ushort_t* gA = h + (size_t)(bm + lane) * F + chunkA * 8;
        ushort_t* lA = Ah + (size_t)(chunkA * 64) * 8;
        __builtin_amdgcn_global_load_lds(
            (const __attribute__((address_space(1))) void*)gA,
            (__attribute__((address_space(3))) void*)lA, 16, 0, 0);
    }

    // -- gather-mean 64 rows: 16 lanes/node, 16 nodes/round, 4 rounds --
    const uint4* h4 = (const uint4*)h;
    for (int rnd = 0; rnd < 4; rnd++) {
        int r = rnd * 16 + (t >> 4);      // local row 0..63
        int n = bm + r;                   // global node (may be pad, deg=0)
        int deg = min(cnt[(size_t)n * cs], ELLW);
        const uint4* el4 = (const uint4*)(ell + ((size_t)n << 6));
        float ax[8], ay[8];
#pragma unroll
        for (int j = 0; j < 8; j++) { ax[j] = 0.f; ay[j] = 0.f; }
        for (int i = 0; i < deg; i += 8) {
            uint4 iv = el4[i >> 3];
            int s0 = iv.x & 0xFFFF, s1 = iv.x >> 16;
            int s2 = iv.y & 0xFFFF, s3 = iv.y >> 16;
            int s4 = iv.z & 0xFFFF, s5 = iv.z >> 16;
            int s6 = iv.w & 0xFFFF, s7 = iv.w >> 16;
            s1 = (i + 1 < deg) ? s1 : ZROW;
            s2 = (i + 2 < deg) ? s2 : ZROW;
            s3 = (i + 3 < deg) ? s3 : ZROW;
            s4 = (i + 4 < deg) ? s4 : ZROW;
            s5 = (i + 5 < deg) ? s5 : ZROW;
            s6 = (i + 6 < deg) ? s6 : ZROW;
            s7 = (i + 7 < deg) ? s7 : ZROW;
            uint4 v0 = h4[(size_t)s0 * 16 + lane16];
            uint4 v1 = h4[(size_t)s1 * 16 + lane16];
            uint4 v2 = h4[(size_t)s2 * 16 + lane16];
            uint4 v3 = h4[(size_t)s3 * 16 + lane16];
            uint4 v4 = h4[(size_t)s4 * 16 + lane16];
            uint4 v5 = h4[(size_t)s5 * 16 + lane16];
            uint4 v6 = h4[(size_t)s6 * 16 + lane16];
            uint4 v7 = h4[(size_t)s7 * 16 + lane16];
            addrow(ax, v0); addrow(ay, v1); addrow(ax, v2); addrow(ay, v3);
            addrow(ax, v4); addrow(ay, v5); addrow(ax, v6); addrow(ay, v7);
        }
        float sc = 1.0f / fmaxf((float)deg, 1.0f);
        uint4 o = make_uint4(
            pack2((ax[0] + ay[0]) * sc, (ax[1] + ay[1]) * sc),
            pack2((ax[2] + ay[2]) * sc, (ax[3] + ay[3]) * sc),
            pack2((ax[4] + ay[4]) * sc, (ax[5] + ay[5]) * sc),
            pack2((ax[6] + ay[6]) * sc, (ax[7] + ay[7]) * sc));
        AggS[lane16 * 64 + r] = o;   // chunk=lane16, row=r
    }
    __syncthreads();   // drains GLL (vmcnt) + ds_writes (lgkm)

    // -- dual GEMM: acc = Agg@Wl^T + Ah@Wr^T; B frags straight from L2 --
    int wm = (w & 1) * 32;
    int wn = (w >> 1) * 64;
    int lrow = lane & 15;
    int kg = lane >> 4;

    f32x4 acc[2][4];
#pragma unroll
    for (int i = 0; i < 2; i++)
#pragma unroll
        for (int j = 0; j < 4; j++) acc[i][j] = (f32x4){0.f, 0.f, 0.f, 0.f};

#pragma unroll
    for (int ks = 0; ks < 4; ks++) {
        int kc = ks * 4 + kg;            // k-chunk 0..15
        bf16x8 aA[2], aH[2], bL[4], bR[4];
#pragma unroll
        for (int i = 0; i < 2; i++) {
            aA[i] = *(const bf16x8*)(Agg + (size_t)(kc * 64 + wm + i * 16 + lrow) * 8);
            aH[i] = *(const bf16x8*)(Ah + (size_t)(kc * 64 + wm + i * 16 + lrow) * 8);
        }
#pragma unroll
        for (int j = 0; j < 4; j++) {
            bL[j] = *(const bf16x8*)(Wl + (size_t)(wn + j * 16 + lrow) * F + kc * 8);
            bR[j] = *(const bf16x8*)(Wr + (size_t)(wn + j * 16 + lrow) * F + kc * 8);
        }
#pragma unroll
        for (int i = 0; i < 2; i++)
#pragma unroll
            for (int j = 0; j < 4; j++) {
                acc[i][j] = __builtin_amdgcn_mfma_f32_16x16x32_bf16(
                    aA[i], bL[j], acc[i][j], 0, 0, 0);
                acc[i][j] = __builtin_amdgcn_mfma_f32_16x16x32_bf16(
                    aH[i], bR[j], acc[i][j], 0, 0, 0);
            }
    }

    // epilogue: C/D map col=lane&15, row=(lane>>4)*4+reg.
    // Pad rows (>=N_NODES) written as EXPLICIT ZEROS (next layer's ZROW).
    int quad = lane >> 4;
#pragma unroll
    for (int j = 0; j < 4; j++) {
        int c = wn + j * 16 + lrow;
        float bj = bias[c];
#pragma unroll
        for (int i = 0; i < 2; i++) {
#pragma unroll
            for (int r = 0; r < 4; r++) {
                int row = bm + wm + i * 16 + quad * 4 + r;
                float v = (row < N_NODES) ? fmaxf(acc[i][j][r] + bj, 0.0f) : 0.0f;
                out[(size_t)row * F + c] = f2bf(v);
            }
        }
    }
}

// ---- mean pool: block per graph, 256 thr (2 halves/col), bsearch ----
__global__ __launch_bounds__(256) void k_pool(const ushort_t* __restrict__ h,
                                              const int* __restrict__ batch,
                                              float* __restrict__ out) {
    __shared__ float red[128];
    int g = blockIdx.x;
    int t = threadIdx.x;
    int col = t & 127;
    int half = t >> 7;
    int lo = 0, hi = N_NODES;
    while (lo < hi) {
        int m = (lo + hi) >> 1;
        if (batch[m] < g) lo = m + 1; else hi = m;
    }
    int start = lo;
    lo = start; hi = N_NODES;
    while (lo < hi) {
        int m = (lo + hi) >> 1;
        if (batch[m] < g + 1) lo = m + 1; else hi = m;
    }
    int end = lo;
    float s = 0.0f;
    for (int n = start + half; n < end; n += 2)
        s += bf2f(h[(size_t)n * F + col]);
    if (half) red[col] = s;
    __syncthreads();
    if (!half)
        out[g * F + col] = (s + red[col]) / fmaxf((float)(end - start), 1.0f);
}

extern "C" void kernel_launch(void* const* d_in, const int* in_sizes, int n_in,
                              void* d_out, int out_size, void* d_ws, size_t ws_size,
                              hipStream_t stream) {
    const float* x   = (const float*)d_in[0];
    const int*   ei  = (const int*)d_in[1];
    const int* batch = (const int*)d_in[2];
    const float* W1l = (const float*)d_in[3];
    const float* W1r = (const float*)d_in[4];
    const float* b1  = (const float*)d_in[5];
    const float* W2l = (const float*)d_in[6];
    const float* W2r = (const float*)d_in[7];
    const float* b2  = (const float*)d_in[8];
    const float* W3l = (const float*)d_in[9];
    const float* W3r = (const float*)d_in[10];
    const float* b3  = (const float*)d_in[11];
    float* out = (float*)d_out;

    const int* src = ei;
    const int* dst = ei + N_EDGES;

    // ws layout: X/HA/HB (3 x 12.81 MB) + WB (0.19) + ell (6.4) + cnt
    ushort_t* X   = (ushort_t*)d_ws;          // NP*128 bf16
    ushort_t* HA  = X + (size_t)NP * F;
    ushort_t* HB  = HA + (size_t)NP * F;
    ushort_t* WB  = HB + (size_t)NP * F;      // 6*16384 bf16
    ushort_t* ell = WB + 6 * 16384;           // 50000*64 ushort
    int* cnt = (int*)(ell + (size_t)50000 * 64);

    // pad cnt to 1 counter / 64B line (stride 16 ints) if ws has room (+3 MB)
    size_t cnt_off = (char*)cnt - (char*)d_ws;
    int cs = (ws_size >= cnt_off + (size_t)50176 * 64) ? 16 : 1;

    const ushort_t* Wb1l = WB;
    const ushort_t* Wb1r = WB + 16384;
    const ushort_t* Wb2l = WB + 2 * 16384;
    const ushort_t* Wb2r = WB + 3 * 16384;
    const ushort_t* Wb3l = WB + 4 * 16384;
    const ushort_t* Wb3r = WB + 5 * 16384;

    (void)hipMemsetAsync(cnt, 0, (size_t)50176 * 4 * cs, stream);
    k_build<<<FILL_BLOCKS + CASTX_BLOCKS + CASTW_BLOCKS, 256, 0, stream>>>(
        x, W1l, W1r, W2l, W2r, W3l, W3r, src, dst, X, WB, cnt, ell, cs);

    const int layerBlocks = NP / 64;  // 782 — whole grid co-resident

    k_layer<<<layerBlocks, 256, 0, stream>>>(X, ell, cnt, Wb1l, Wb1r, b1, HA, cs);
    k_layer<<<layerBlocks, 256, 0, stream>>>(HA, ell, cnt, Wb2l, Wb2r, b2, HB, cs);
    k_layer<<<layerBlocks, 256, 0, stream>>>(HB, ell, cnt, Wb3l, Wb3r, b3, HA, cs);

    k_pool<<<N_GRAPHS, 256, 0, stream>>>(HA, batch, out);
}

// Round 5
// 309.453 us; speedup vs baseline: 1.0171x; 1.0171x over previous
//
#include <hip/hip_runtime.h>

// GraphSAGE 3-layer encoder. R14: R13 fused k_layer +
// (a) gather ILP-16 (16 row-loads in flight/thread; degs hoisted; summation
//     order identical to ILP-8 so numerics are bit-identical),
// (b) Agg LDS XOR swizzle (row ^ (chunk&7)) on write+read: kills the 16-way
//     ds_write_b128 bank conflict (700k conflict cycles/dispatch).
#define N_NODES 50000
#define NP 50048          // padded to 782*64 rows
#define N_EDGES 800000
#define N_GRAPHS 512
#define F 128
#define ELLW 64           // Poisson(16): P(deg>=64) ~ e^-125
#define ZROW N_NODES      // guaranteed all-zero row in X/HA/HB

#define FILL_BLOCKS 3125    // N_EDGES/256, 1 edge/thread
#define CASTX_BLOCKS 3128   // NP*F/8/256
#define CASTW_BLOCKS 48     // 6*16384/8/256

typedef __bf16 bf16x8 __attribute__((ext_vector_type(8)));
typedef float f32x4 __attribute__((ext_vector_type(4)));
typedef float f32x4v __attribute__((ext_vector_type(4)));   // nt-load friendly
typedef unsigned short ushort_t;
typedef unsigned int uint_t;

__device__ inline ushort_t f2bf(float f) {  // RTNE
    uint_t u = __float_as_uint(f);
    u += 0x7FFFu + ((u >> 16) & 1u);
    return (ushort_t)(u >> 16);
}
__device__ inline float bf2f(ushort_t u) {
    return __uint_as_float(((uint_t)u) << 16);
}
__device__ inline uint_t pack2(float a, float b) {
    return (uint_t)f2bf(a) | ((uint_t)f2bf(b) << 16);
}
__device__ inline void addrow(float* a, uint4 v) {
    a[0] += __uint_as_float(v.x << 16); a[1] += __uint_as_float(v.x & 0xFFFF0000u);
    a[2] += __uint_as_float(v.y << 16); a[3] += __uint_as_float(v.y & 0xFFFF0000u);
    a[4] += __uint_as_float(v.z << 16); a[5] += __uint_as_float(v.z & 0xFFFF0000u);
    a[6] += __uint_as_float(v.w << 16); a[7] += __uint_as_float(v.w & 0xFFFF0000u);
}

// ---- merged build: ELL fill (1 edge/thread) + bf16 casts ----
__global__ __launch_bounds__(256) void k_build(
    const float* __restrict__ x,
    const float* __restrict__ w0, const float* __restrict__ w1,
    const float* __restrict__ w2, const float* __restrict__ w3,
    const float* __restrict__ w4, const float* __restrict__ w5,
    const int* __restrict__ src, const int* __restrict__ dst,
    ushort_t* __restrict__ X, ushort_t* __restrict__ WB,
    int* __restrict__ cnt, ushort_t* __restrict__ ell, int cs) {
    int b = blockIdx.x;
    int t = threadIdx.x;
    if (b < FILL_BLOCKS) {
        int e = b * 256 + t;
        int d = dst[e];
        int pos = atomicAdd(&cnt[(size_t)d * cs], 1);
        if (pos < ELLW) ell[((size_t)d << 6) + pos] = (ushort_t)src[e];
    } else if (b < FILL_BLOCKS + CASTX_BLOCKS) {
        int i = ((b - FILL_BLOCKS) * 256 + t) * 8;
        uint4 o = make_uint4(0, 0, 0, 0);
        if (i < N_NODES * F) {  // boundary 8-aligned: no straddle
            f32x4v v0 = __builtin_nontemporal_load((const f32x4v*)&x[i]);
            f32x4v v1 = __builtin_nontemporal_load((const f32x4v*)&x[i + 4]);
            o = make_uint4(pack2(v0.x, v0.y), pack2(v0.z, v0.w),
                           pack2(v1.x, v1.y), pack2(v1.z, v1.w));
        }
        *(uint4*)&X[i] = o;  // pads (>=N_NODES) written as zeros: ZROW source
    } else {
        int idx = (b - FILL_BLOCKS - CASTX_BLOCKS) * 256 + t;  // 8-elem groups
        int m = idx >> 11;
        int o = (idx & 2047) * 8;
        const float* s = w0;
        if (m == 1) s = w1; else if (m == 2) s = w2; else if (m == 3) s = w3;
        else if (m == 4) s = w4; else if (m == 5) s = w5;
        float4 v0 = *(const float4*)&s[o];
        float4 v1 = *(const float4*)&s[o + 4];
        *(uint4*)&WB[m * 16384 + o] =
            make_uint4(pack2(v0.x, v0.y), pack2(v0.z, v0.w),
                       pack2(v1.x, v1.y), pack2(v1.z, v1.w));
    }
}

// ---- fused layer: gather-mean + dual GEMM (agg@Wl + h@Wr) + bias + relu ----
// 782 blocks x 256 thr. LDS: Ah 16KB + Aagg 16KB, [kchunk][row]x16B layout.
__global__ __launch_bounds__(256) void k_layer(const ushort_t* __restrict__ h,
                                               const ushort_t* __restrict__ ell,
                                               const int* __restrict__ cnt,
                                               const ushort_t* __restrict__ Wl,
                                               const ushort_t* __restrict__ Wr,
                                               const float* __restrict__ bias,
                                               ushort_t* __restrict__ out, int cs) {
    __shared__ uint4 AhS[1024];    // 16 KB: h rows, chunk-major [16][64] x16B
    __shared__ uint4 AggS[1024];   // 16 KB: agg rows, swizzled row^(chunk&7)
    ushort_t* Ah = (ushort_t*)AhS;
    ushort_t* Agg = (ushort_t*)AggS;

    int t = threadIdx.x;
    int w = t >> 6;
    int lane = t & 63;
    int bm = blockIdx.x * 64;
    int lane16 = t & 15;

    // -- stage own h rows (async GLL, drains at the barrier) --
#pragma unroll
    for (int p = 0; p < 4; p++) {
        int chunkA = p * 4 + w;
        const ushort_t* gA = h + (size_t)(bm + lane) * F + chunkA * 8;
        ushort_t* lA = Ah + (size_t)(chunkA * 64) * 8;
        __builtin_amdgcn_global_load_lds(
            (const __attribute__((address_space(1))) void*)gA,
            (__attribute__((address_space(3))) void*)lA, 16, 0, 0);
    }

    // -- gather-mean 64 rows: 16 lanes/node, 16 nodes/round, 4 rounds.
    // degs hoisted; ILP-16 inner (2 uint4 index loads + 16 row loads in
    // flight). Even edges -> ax, odd -> ay: summation order identical to the
    // ILP-8 version (bit-exact numerics).
    const uint4* h4 = (const uint4*)h;
    int degs[4];
#pragma unroll
    for (int rnd = 0; rnd < 4; rnd++)
        degs[rnd] = min(cnt[(size_t)(bm + rnd * 16 + (t >> 4)) * cs], ELLW);

#pragma unroll
    for (int rnd = 0; rnd < 4; rnd++) {
        int r = rnd * 16 + (t >> 4);      // local row 0..63
        int n = bm + r;                   // global node (may be pad, deg=0)
        int deg = degs[rnd];
        const uint4* el4 = (const uint4*)(ell + ((size_t)n << 6));
        float ax[8], ay[8];
#pragma unroll
        for (int j = 0; j < 8; j++) { ax[j] = 0.f; ay[j] = 0.f; }
        for (int base = 0; base < deg; base += 16) {
            uint4 iv0 = el4[(base >> 3)];
            uint4 iv1 = el4[(base >> 3) + 1];   // ell row has 8 uint4: in-bounds
            int s0  = iv0.x & 0xFFFF, s1  = iv0.x >> 16;
            int s2  = iv0.y & 0xFFFF, s3  = iv0.y >> 16;
            int s4  = iv0.z & 0xFFFF, s5  = iv0.z >> 16;
            int s6  = iv0.w & 0xFFFF, s7  = iv0.w >> 16;
            int s8  = iv1.x & 0xFFFF, s9  = iv1.x >> 16;
            int s10 = iv1.y & 0xFFFF, s11 = iv1.y >> 16;
            int s12 = iv1.z & 0xFFFF, s13 = iv1.z >> 16;
            int s14 = iv1.w & 0xFFFF, s15 = iv1.w >> 16;
            // beyond-deg entries are garbage: clamp to the all-zero row
            s1  = (base + 1  < deg) ? s1  : ZROW;
            s2  = (base + 2  < deg) ? s2  : ZROW;
            s3  = (base + 3  < deg) ? s3  : ZROW;
            s4  = (base + 4  < deg) ? s4  : ZROW;
            s5  = (base + 5  < deg) ? s5  : ZROW;
            s6  = (base + 6  < deg) ? s6  : ZROW;
            s7  = (base + 7  < deg) ? s7  : ZROW;
            s8  = (base + 8  < deg) ? s8  : ZROW;
            s9  = (base + 9  < deg) ? s9  : ZROW;
            s10 = (base + 10 < deg) ? s10 : ZROW;
            s11 = (base + 11 < deg) ? s11 : ZROW;
            s12 = (base + 12 < deg) ? s12 : ZROW;
            s13 = (base + 13 < deg) ? s13 : ZROW;
            s14 = (base + 14 < deg) ? s14 : ZROW;
            s15 = (base + 15 < deg) ? s15 : ZROW;
            uint4 v0  = h4[(size_t)s0  * 16 + lane16];
            uint4 v1  = h4[(size_t)s1  * 16 + lane16];
            uint4 v2  = h4[(size_t)s2  * 16 + lane16];
            uint4 v3  = h4[(size_t)s3  * 16 + lane16];
            uint4 v4  = h4[(size_t)s4  * 16 + lane16];
            uint4 v5  = h4[(size_t)s5  * 16 + lane16];
            uint4 v6  = h4[(size_t)s6  * 16 + lane16];
            uint4 v7  = h4[(size_t)s7  * 16 + lane16];
            uint4 v8  = h4[(size_t)s8  * 16 + lane16];
            uint4 v9  = h4[(size_t)s9  * 16 + lane16];
            uint4 v10 = h4[(size_t)s10 * 16 + lane16];
            uint4 v11 = h4[(size_t)s11 * 16 + lane16];
            uint4 v12 = h4[(size_t)s12 * 16 + lane16];
            uint4 v13 = h4[(size_t)s13 * 16 + lane16];
            uint4 v14 = h4[(size_t)s14 * 16 + lane16];
            uint4 v15 = h4[(size_t)s15 * 16 + lane16];
            addrow(ax, v0);  addrow(ay, v1);
            addrow(ax, v2);  addrow(ay, v3);
            addrow(ax, v4);  addrow(ay, v5);
            addrow(ax, v6);  addrow(ay, v7);
            addrow(ax, v8);  addrow(ay, v9);
            addrow(ax, v10); addrow(ay, v11);
            addrow(ax, v12); addrow(ay, v13);
            addrow(ax, v14); addrow(ay, v15);
        }
        float sc = 1.0f / fmaxf((float)deg, 1.0f);
        uint4 o = make_uint4(
            pack2((ax[0] + ay[0]) * sc, (ax[1] + ay[1]) * sc),
            pack2((ax[2] + ay[2]) * sc, (ax[3] + ay[3]) * sc),
            pack2((ax[4] + ay[4]) * sc, (ax[5] + ay[5]) * sc),
            pack2((ax[6] + ay[6]) * sc, (ax[7] + ay[7]) * sc));
        AggS[lane16 * 64 + (r ^ (lane16 & 7))] = o;   // swizzled: chunk=lane16
    }
    __syncthreads();   // drains GLL (vmcnt) + ds_writes (lgkm)

    // -- dual GEMM: acc = Agg@Wl^T + Ah@Wr^T; B frags straight from L2 --
    int wm = (w & 1) * 32;
    int wn = (w >> 1) * 64;
    int lrow = lane & 15;
    int kg = lane >> 4;

    f32x4 acc[2][4];
#pragma unroll
    for (int i = 0; i < 2; i++)
#pragma unroll
        for (int j = 0; j < 4; j++) acc[i][j] = (f32x4){0.f, 0.f, 0.f, 0.f};

#pragma unroll
    for (int ks = 0; ks < 4; ks++) {
        int kc = ks * 4 + kg;            // k-chunk 0..15
        bf16x8 aA[2], aH[2], bL[4], bR[4];
#pragma unroll
        for (int i = 0; i < 2; i++) {
            int row = wm + i * 16 + lrow;
            aA[i] = *(const bf16x8*)(Agg +
                (size_t)(kc * 64 + (row ^ (kc & 7))) * 8);   // match swizzle
            aH[i] = *(const bf16x8*)(Ah + (size_t)(kc * 64 + row) * 8);
        }
#pragma unroll
        for (int j = 0; j < 4; j++) {
            bL[j] = *(const bf16x8*)(Wl + (size_t)(wn + j * 16 + lrow) * F + kc * 8);
            bR[j] = *(const bf16x8*)(Wr + (size_t)(wn + j * 16 + lrow) * F + kc * 8);
        }
#pragma unroll
        for (int i = 0; i < 2; i++)
#pragma unroll
            for (int j = 0; j < 4; j++) {
                acc[i][j] = __builtin_amdgcn_mfma_f32_16x16x32_bf16(
                    aA[i], bL[j], acc[i][j], 0, 0, 0);
                acc[i][j] = __builtin_amdgcn_mfma_f32_16x16x32_bf16(
                    aH[i], bR[j], acc[i][j], 0, 0, 0);
            }
    }

    // epilogue: C/D map col=lane&15, row=(lane>>4)*4+reg.
    // Pad rows (>=N_NODES) written as EXPLICIT ZEROS (next layer's ZROW).
    int quad = lane >> 4;
#pragma unroll
    for (int j = 0; j < 4; j++) {
        int c = wn + j * 16 + lrow;
        float bj = bias[c];
#pragma unroll
        for (int i = 0; i < 2; i++) {
#pragma unroll
            for (int r = 0; r < 4; r++) {
                int row = bm + wm + i * 16 + quad * 4 + r;
                float v = (row < N_NODES) ? fmaxf(acc[i][j][r] + bj, 0.0f) : 0.0f;
                out[(size_t)row * F + c] = f2bf(v);
            }
        }
    }
}

// ---- mean pool: block per graph, 256 thr (2 halves/col), bsearch ----
__global__ __launch_bounds__(256) void k_pool(const ushort_t* __restrict__ h,
                                              const int* __restrict__ batch,
                                              float* __restrict__ out) {
    __shared__ float red[128];
    int g = blockIdx.x;
    int t = threadIdx.x;
    int col = t & 127;
    int half = t >> 7;
    int lo = 0, hi = N_NODES;
    while (lo < hi) {
        int m = (lo + hi) >> 1;
        if (batch[m] < g) lo = m + 1; else hi = m;
    }
    int start = lo;
    lo = start; hi = N_NODES;
    while (lo < hi) {
        int m = (lo + hi) >> 1;
        if (batch[m] < g + 1) lo = m + 1; else hi = m;
    }
    int end = lo;
    float s = 0.0f;
    for (int n = start + half; n < end; n += 2)
        s += bf2f(h[(size_t)n * F + col]);
    if (half) red[col] = s;
    __syncthreads();
    if (!half)
        out[g * F + col] = (s + red[col]) / fmaxf((float)(end - start), 1.0f);
}

extern "C" void kernel_launch(void* const* d_in, const int* in_sizes, int n_in,
                              void* d_out, int out_size, void* d_ws, size_t ws_size,
                              hipStream_t stream) {
    const float* x   = (const float*)d_in[0];
    const int*   ei  = (const int*)d_in[1];
    const int* batch = (const int*)d_in[2];
    const float* W1l = (const float*)d_in[3];
    const float* W1r = (const float*)d_in[4];
    const float* b1  = (const float*)d_in[5];
    const float* W2l = (const float*)d_in[6];
    const float* W2r = (const float*)d_in[7];
    const float* b2  = (const float*)d_in[8];
    const float* W3l = (const float*)d_in[9];
    const float* W3r = (const float*)d_in[10];
    const float* b3  = (const float*)d_in[11];
    float* out = (float*)d_out;

    const int* src = ei;
    const int* dst = ei + N_EDGES;

    // ws layout: X/HA/HB (3 x 12.81 MB) + WB (0.19) + ell (6.4) + cnt
    ushort_t* X   = (ushort_t*)d_ws;          // NP*128 bf16
    ushort_t* HA  = X + (size_t)NP * F;
    ushort_t* HB  = HA + (size_t)NP * F;
    ushort_t* WB  = HB + (size_t)NP * F;      // 6*16384 bf16
    ushort_t* ell = WB + 6 * 16384;           // 50000*64 ushort
    int* cnt = (int*)(ell + (size_t)50000 * 64);

    // pad cnt to 1 counter / 64B line (stride 16 ints) if ws has room (+3 MB)
    size_t cnt_off = (char*)cnt - (char*)d_ws;
    int cs = (ws_size >= cnt_off + (size_t)50176 * 64) ? 16 : 1;

    const ushort_t* Wb1l = WB;
    const ushort_t* Wb1r = WB + 16384;
    const ushort_t* Wb2l = WB + 2 * 16384;
    const ushort_t* Wb2r = WB + 3 * 16384;
    const ushort_t* Wb3l = WB + 4 * 16384;
    const ushort_t* Wb3r = WB + 5 * 16384;

    (void)hipMemsetAsync(cnt, 0, (size_t)50176 * 4 * cs, stream);
    k_build<<<FILL_BLOCKS + CASTX_BLOCKS + CASTW_BLOCKS, 256, 0, stream>>>(
        x, W1l, W1r, W2l, W2r, W3l, W3r, src, dst, X, WB, cnt, ell, cs);

    const int layerBlocks = NP / 64;  // 782 — whole grid co-resident

    k_layer<<<layerBlocks, 256, 0, stream>>>(X, ell, cnt, Wb1l, Wb1r, b1, HA, cs);
    k_layer<<<layerBlocks, 256, 0, stream>>>(HA, ell, cnt, Wb2l, Wb2r, b2, HB, cs);
    k_layer<<<layerBlocks, 256, 0, stream>>>(HB, ell, cnt, Wb3l, Wb3r, b3, HA, cs);

    k_pool<<<N_GRAPHS, 256, 0, stream>>>(HA, batch, out);
}